// Round 15
// baseline (80.930 us; speedup 1.0000x reference)
//
#include <hip/hip_runtime.h>
#include <math.h>

#define NB   4
#define CIN  512
#define HID  64
#define NK   11     // NUM_CLASSES+1
#define H1   60
#define W1p  80
#define P1   4800
#define H2   30
#define W2p  40
#define P2   1200
#define HO   480
#define WOp  640
#define NP1  (NB*P1)    // 19200
#define NP2  (NB*P2)    // 4800
#define PLANE ((size_t)HO*WOp)                  // 307200
#define SEG_OFF ((size_t)NB*NK*PLANE)           // 13,516,800
#define BBX_OFF (SEG_OFF + (size_t)NB*PLANE)    // 14,745,600

// ws layout in floats: [0,65536) = packed bf16 W-frags (131072 ushort, both convs)
#define WS_F2  65536                            // 4800*64 = 307,200
#define WS_SEG (WS_F2 + NP2*64)                 // 19200 ints

typedef __attribute__((ext_vector_type(8))) short bf16x8;
typedef __attribute__((ext_vector_type(4))) float f32x4;

// RNE fp32 -> bf16, returns bits, writes residual x - bf16(x)
__device__ __forceinline__ unsigned short bfsplit(float x, float& resid) {
    unsigned u = __float_as_uint(x);
    unsigned t = u + 0x7FFFu + ((u >> 16) & 1u);
    unsigned short h = (unsigned short)(t >> 16);
    resid = x - __uint_as_float((unsigned)h << 16);
    return h;
}

// -------- pack weights into chunk-major A-fragment pages, 2-plane split -----
// (identical to r13, which passed at absmax 3.9e-3)
__global__ __launch_bounds__(256) void pack_w(const float* __restrict__ w1,
                                              const float* __restrict__ w2,
                                              float* __restrict__ ws) {
    int i = blockIdx.x * 256 + threadIdx.x;   // 0..32767
    if (i >= HID * CIN) return;
    int o = i >> 9, c = i & 511;
    int chunk = c >> 6, r = c & 63, ks2 = r >> 5, k = r & 31;
    int lane = (o & 15) + ((k >> 3) << 4);
    int mt = o >> 4;
    int d = ((((chunk * 2 + ks2) * 4 + mt) * 2) * 64 + lane) * 8 + (k & 7);
    unsigned short* q = (unsigned short*)ws;
    float r1;
    unsigned short h = bfsplit(w1[i], r1);
    unsigned short m = bfsplit(r1, r1);
    q[d] = h; q[d + 512] = m;                 // plane stride = 64*8 = 512
    h = bfsplit(w2[i], r1); m = bfsplit(r1, r1);
    q[65536 + d] = h; q[65536 + d + 512] = m;
}

// -------- conv2 (f2) via MFMA, r13 core, 76 blocks -> ws -------------------
__global__ __launch_bounds__(256) void conv_f2(const float* __restrict__ f2,
                                               const float* __restrict__ b2v,
                                               float* __restrict__ ws) {
    __shared__ int xpl[16 * 256];
    __shared__ int alds[16 * 256];
    int u = blockIdx.x;                        // 0..75
    int b = u / 19, ti = u % 19;
    int px0 = ti * 64; if (px0 > P2 - 64) px0 = P2 - 64;   // tail overlap benign
    const float* X = f2 + (size_t)b * CIN * P2;
    const int P = P2;
    const int* WPK = (const int*)((const unsigned short*)ws + 65536);
    float* Cout = ws + WS_F2 + (size_t)b * P2 * 64;

    int tid  = threadIdx.x;
    int lane = tid & 63;
    int wv   = tid >> 6;
    int pcol = lane & 15, kgrp = lane >> 4;
    const float* Xg = X + px0 + wv * 16 + pcol;

    float xvA[16], xvB[16];
    int4 areg[4];
    auto loadX = [&](float* dst, int cc) {
#pragma unroll
        for (int ks2 = 0; ks2 < 2; ++ks2)
#pragma unroll
            for (int j = 0; j < 8; ++j)
                dst[ks2 * 8 + j] = Xg[(size_t)(cc * 64 + ks2 * 32 + kgrp * 8 + j) * P];
    };
    auto loadA = [&](int cc) {
#pragma unroll
        for (int p = 0; p < 4; ++p)
            areg[p] = *(const int4*)&WPK[cc * 4096 + p * 1024 + tid * 4];
    };
    auto stage = [&](const float* xs) {
#pragma unroll
        for (int ks2 = 0; ks2 < 2; ++ks2) {
            int hh[8], mm[8];
#pragma unroll
            for (int j = 0; j < 8; ++j) {
                float r;
                unsigned short h = bfsplit(xs[ks2 * 8 + j], r);
                unsigned short m = bfsplit(r, r);
                hh[j] = h; mm[j] = m;
            }
            int4 H, M;
            ((int*)&H)[0] = hh[0] | (hh[1] << 16); ((int*)&H)[1] = hh[2] | (hh[3] << 16);
            ((int*)&H)[2] = hh[4] | (hh[5] << 16); ((int*)&H)[3] = hh[6] | (hh[7] << 16);
            ((int*)&M)[0] = mm[0] | (mm[1] << 16); ((int*)&M)[1] = mm[2] | (mm[3] << 16);
            ((int*)&M)[2] = mm[4] | (mm[5] << 16); ((int*)&M)[3] = mm[6] | (mm[7] << 16);
            int pg = ((wv * 2 + ks2) * 2) * 256 + lane * 4;
            *(int4*)&xpl[pg]       = H;
            *(int4*)&xpl[pg + 256] = M;
        }
#pragma unroll
        for (int p = 0; p < 4; ++p)
            *(int4*)&alds[p * 1024 + tid * 4] = areg[p];
    };

    union FU { int4 q; bf16x8 v; };
    f32x4 acc[4];
#pragma unroll
    for (int st = 0; st < 4; ++st) acc[st] = (f32x4){0.f, 0.f, 0.f, 0.f};

    loadX(xvA, 0); loadA(0); stage(xvA); loadX(xvA, 1);
    __syncthreads();
    for (int c = 0; c < 8; ++c) {
        if (c < 7) loadA(c + 1);
        if (c < 6) loadX(xvB, c + 2);
#pragma unroll
        for (int ks2 = 0; ks2 < 2; ++ks2) {
            FU Ah, Am;
            int pa = ((ks2 * 4 + wv) * 2) * 256 + lane * 4;
            Ah.q = *(const int4*)&alds[pa];
            Am.q = *(const int4*)&alds[pa + 256];
#pragma unroll
            for (int st = 0; st < 4; ++st) {
                FU Bh, Bm;
                int pb = ((st * 2 + ks2) * 2) * 256 + lane * 4;
                Bh.q = *(const int4*)&xpl[pb];
                Bm.q = *(const int4*)&xpl[pb + 256];
                acc[st] = __builtin_amdgcn_mfma_f32_16x16x32_bf16(Ah.v, Bh.v, acc[st], 0, 0, 0);
                acc[st] = __builtin_amdgcn_mfma_f32_16x16x32_bf16(Ah.v, Bm.v, acc[st], 0, 0, 0);
                acc[st] = __builtin_amdgcn_mfma_f32_16x16x32_bf16(Am.v, Bh.v, acc[st], 0, 0, 0);
                acc[st] = __builtin_amdgcn_mfma_f32_16x16x32_bf16(Am.v, Bm.v, acc[st], 0, 0, 0);
            }
        }
        __syncthreads();
        if (c < 7) {
            stage(xvA);
            __syncthreads();
#pragma unroll
            for (int i2 = 0; i2 < 16; ++i2) xvA[i2] = xvB[i2];
        }
    }
    int r4 = (lane >> 4) * 4;
    float4 bb = *(const float4*)(b2v + wv * 16 + r4);
#pragma unroll
    for (int st = 0; st < 4; ++st) {
        int px = px0 + st * 16 + pcol;
        float a0 = acc[st][0] + bb.x, a1 = acc[st][1] + bb.y;
        float a2 = acc[st][2] + bb.z, a3 = acc[st][3] + bb.w;
        *(float4*)(Cout + (size_t)px * 64 + wv * 16 + r4) =
            make_float4(a0 > 0.f ? a0 : 0.f, a1 > 0.f ? a1 : 0.f,
                        a2 > 0.f ? a2 : 0.f, a3 > 0.f ? a3 : 0.f);
    }
}

// -------- mega: conv1(f1, MFMA r13 core) + head + 8x upsample stores --------
// 300 blocks x 256 thr. After the K-loop the 32KB smem is REUSED:
// c1[64][68] + prob[64][13] + swo[704] + sbo. Wave 0 computes the 11-way head
// per pixel; all threads then write the upsampled prob+seg planes to d_out.
__global__ __launch_bounds__(256) void mega_kernel(const float* __restrict__ f1,
                                                   const float* __restrict__ b1v,
                                                   const float* __restrict__ wo,
                                                   const float* __restrict__ bo,
                                                   float* __restrict__ ws,
                                                   float* __restrict__ out) {
    __shared__ int smem[8192];          // 32KB: conv phase xpl|alds, then head
    int* xpl  = smem;
    int* alds = smem + 4096;
    int t = blockIdx.x;                 // 0..299
    int b = t / 75, ti = t % 75;
    int px0 = ti * 64;
    const float* X = f1 + (size_t)b * CIN * P1;
    const int P = P1;
    const int* WPK = (const int*)ws;    // conv1 pages at offset 0

    int tid  = threadIdx.x;
    int lane = tid & 63;
    int wv   = tid >> 6;
    int pcol = lane & 15, kgrp = lane >> 4;
    const float* Xg = X + px0 + wv * 16 + pcol;

    float xvA[16], xvB[16];
    int4 areg[4];
    auto loadX = [&](float* dst, int cc) {
#pragma unroll
        for (int ks2 = 0; ks2 < 2; ++ks2)
#pragma unroll
            for (int j = 0; j < 8; ++j)
                dst[ks2 * 8 + j] = Xg[(size_t)(cc * 64 + ks2 * 32 + kgrp * 8 + j) * P];
    };
    auto loadA = [&](int cc) {
#pragma unroll
        for (int p = 0; p < 4; ++p)
            areg[p] = *(const int4*)&WPK[cc * 4096 + p * 1024 + tid * 4];
    };
    auto stage = [&](const float* xs) {
#pragma unroll
        for (int ks2 = 0; ks2 < 2; ++ks2) {
            int hh[8], mm[8];
#pragma unroll
            for (int j = 0; j < 8; ++j) {
                float r;
                unsigned short h = bfsplit(xs[ks2 * 8 + j], r);
                unsigned short m = bfsplit(r, r);
                hh[j] = h; mm[j] = m;
            }
            int4 H, M;
            ((int*)&H)[0] = hh[0] | (hh[1] << 16); ((int*)&H)[1] = hh[2] | (hh[3] << 16);
            ((int*)&H)[2] = hh[4] | (hh[5] << 16); ((int*)&H)[3] = hh[6] | (hh[7] << 16);
            ((int*)&M)[0] = mm[0] | (mm[1] << 16); ((int*)&M)[1] = mm[2] | (mm[3] << 16);
            ((int*)&M)[2] = mm[4] | (mm[5] << 16); ((int*)&M)[3] = mm[6] | (mm[7] << 16);
            int pg = ((wv * 2 + ks2) * 2) * 256 + lane * 4;
            *(int4*)&xpl[pg]       = H;
            *(int4*)&xpl[pg + 256] = M;
        }
#pragma unroll
        for (int p = 0; p < 4; ++p)
            *(int4*)&alds[p * 1024 + tid * 4] = areg[p];
    };

    union FU { int4 q; bf16x8 v; };
    f32x4 acc[4];
#pragma unroll
    for (int st = 0; st < 4; ++st) acc[st] = (f32x4){0.f, 0.f, 0.f, 0.f};

    loadX(xvA, 0); loadA(0); stage(xvA); loadX(xvA, 1);
    __syncthreads();
    for (int c = 0; c < 8; ++c) {
        if (c < 7) loadA(c + 1);
        if (c < 6) loadX(xvB, c + 2);
#pragma unroll
        for (int ks2 = 0; ks2 < 2; ++ks2) {
            FU Ah, Am;
            int pa = ((ks2 * 4 + wv) * 2) * 256 + lane * 4;
            Ah.q = *(const int4*)&alds[pa];
            Am.q = *(const int4*)&alds[pa + 256];
#pragma unroll
            for (int st = 0; st < 4; ++st) {
                FU Bh, Bm;
                int pb = ((st * 2 + ks2) * 2) * 256 + lane * 4;
                Bh.q = *(const int4*)&xpl[pb];
                Bm.q = *(const int4*)&xpl[pb + 256];
                acc[st] = __builtin_amdgcn_mfma_f32_16x16x32_bf16(Ah.v, Bh.v, acc[st], 0, 0, 0);
                acc[st] = __builtin_amdgcn_mfma_f32_16x16x32_bf16(Ah.v, Bm.v, acc[st], 0, 0, 0);
                acc[st] = __builtin_amdgcn_mfma_f32_16x16x32_bf16(Am.v, Bh.v, acc[st], 0, 0, 0);
                acc[st] = __builtin_amdgcn_mfma_f32_16x16x32_bf16(Am.v, Bm.v, acc[st], 0, 0, 0);
            }
        }
        __syncthreads();
        if (c < 7) {
            stage(xvA);
            __syncthreads();
#pragma unroll
            for (int i2 = 0; i2 < 16; ++i2) xvA[i2] = xvB[i2];
        }
    }
    __syncthreads();                    // conv done; smem is now free

    // ---- phase 2 layout (floats) ----
    float* c1   = (float*)smem;         // [64][68] = 4352
    float* prob = c1 + 4352;            // [64][13] = 832
    float* swo  = prob + 832;           // 704
    float* sbo  = swo + 704;            // 11

    // write relu(conv1+bias) to c1; C/D layout: col=lane&15, row=(lane>>4)*4+reg
    int r4 = (lane >> 4) * 4;
    float4 bb = *(const float4*)(b1v + wv * 16 + r4);
#pragma unroll
    for (int st = 0; st < 4; ++st) {
        float a0 = acc[st][0] + bb.x, a1 = acc[st][1] + bb.y;
        float a2 = acc[st][2] + bb.z, a3 = acc[st][3] + bb.w;
        *(float4*)&c1[(st * 16 + pcol) * 68 + wv * 16 + r4] =
            make_float4(a0 > 0.f ? a0 : 0.f, a1 > 0.f ? a1 : 0.f,
                        a2 > 0.f ? a2 : 0.f, a3 > 0.f ? a3 : 0.f);
    }
    for (int i = tid; i < NK * 64; i += 256) swo[i] = wo[i];
    if (tid < NK) sbo[tid] = bo[tid];
    __syncthreads();

    // ---- head: wave 0, lane = pixel ----
    if (tid < 64) {
        int px_g = px0 + tid;
        int y = px_g / W1p, x = px_g % W1p;
        int qp = (y >> 1) * W2p + (x >> 1);
        const float* f2p = ws + WS_F2 + ((size_t)b * P2 + qp) * 64;
        const float* c1p = c1 + tid * 68;
        float ok[NK];
#pragma unroll
        for (int k = 0; k < NK; ++k) ok[k] = sbo[k];
#pragma unroll
        for (int o4 = 0; o4 < 16; ++o4) {
            float4 cq = *(const float4*)(c1p + o4 * 4);
            float4 fq = *(const float4*)(f2p + o4 * 4);
            float co[4] = { cq.x + fq.x, cq.y + fq.y, cq.z + fq.z, cq.w + fq.w };
#pragma unroll
            for (int j = 0; j < 4; ++j) {
                int o = o4 * 4 + j;
#pragma unroll
                for (int k = 0; k < NK; ++k) ok[k] = fmaf(co[j], swo[k * 64 + o], ok[k]);
            }
        }
        float m = 0.f;
#pragma unroll
        for (int k = 0; k < NK; ++k) {
            ok[k] = ok[k] > 0.f ? ok[k] : 0.f;
            if (ok[k] > m) m = ok[k];
        }
        float e[NK], sum = 0.f;
#pragma unroll
        for (int k = 0; k < NK; ++k) { e[k] = expf(ok[k] - m); sum += e[k]; }
        float inv = 1.f / sum;
        int arg = 0; float best = ok[0];
#pragma unroll
        for (int k = 1; k < NK; ++k) { if (ok[k] > best) { best = ok[k]; arg = k; } }
#pragma unroll
        for (int k = 0; k < NK; ++k) prob[tid * 13 + k] = e[k] * inv;
        prob[tid * 13 + 11] = (float)arg;
        ((int*)(ws + WS_SEG))[b * P1 + px_g] = arg;
    }
    __syncthreads();

    // ---- 8x upsample stores: 12 planes x 8 dy x 64 px x 2 float4 ----
    for (int id = tid; id < 12 * 8 * 128; id += 256) {
        int k   = id >> 10;
        int rem = id & 1023;
        int dy  = rem >> 7;
        int g   = rem & 127;
        int j   = g >> 1;
        int q   = g & 1;
        int px_g = px0 + j;
        int y = px_g / W1p, x = px_g % W1p;
        float v = prob[j * 13 + k];
        size_t base;
        if (k < NK)
            base = (((size_t)(b * NK + k) * HO) + (size_t)(y * 8 + dy)) * WOp + x * 8 + q * 4;
        else
            base = SEG_OFF + (((size_t)b * HO) + (size_t)(y * 8 + dy)) * WOp + x * 8 + q * 4;
        *(float4*)(out + base) = make_float4(v, v, v, v);
    }
}

// ---------------- bbox: per-(batch,class) min/max/count over 60x80 seg ------
__global__ __launch_bounds__(256) void bbx_kernel(const float* __restrict__ ws,
                                                  float* __restrict__ out) {
    __shared__ int cnt[10], xmn[10], xmx[10], ymn[10], ymx[10];
    int b = blockIdx.x;
    int t = threadIdx.x;
    if (t < 10) { cnt[t] = 0; xmn[t] = 1 << 30; xmx[t] = -1; ymn[t] = 1 << 30; ymx[t] = -1; }
    __syncthreads();
    const int* seg = (const int*)(ws + WS_SEG) + b * P1;
    for (int p = t; p < P1; p += 256) {
        int s = seg[p];
        if (s >= 1 && s <= 9) {
            int y = p / W1p, x = p % W1p;
            atomicAdd(&cnt[s], 1);
            atomicMin(&xmn[s], x); atomicMax(&xmx[s], x);
            atomicMin(&ymn[s], y); atomicMax(&ymx[s], y);
        }
    }
    __syncthreads();
    if (t < 9) {
        int c = t + 1;
        bool valid = cnt[c] * 64 >= 500;    // upsampled count = 64*count
        float r[6];
        if (valid) {
            r[0] = (float)b;
            r[1] = (float)(xmn[c] * 8);
            r[2] = (float)(ymn[c] * 8);
            r[3] = (float)(xmx[c] * 8 + 7);
            r[4] = (float)(ymx[c] * 8 + 7);
            r[5] = (float)c;
        } else {
            for (int i = 0; i < 6; ++i) r[i] = -1.f;
        }
        float* row = out + BBX_OFF + (size_t)(b * 9 + t) * 6;
        for (int i = 0; i < 6; ++i) row[i] = r[i];
    }
}

extern "C" void kernel_launch(void* const* d_in, const int* in_sizes, int n_in,
                              void* d_out, int out_size, void* d_ws, size_t ws_size,
                              hipStream_t stream) {
    const float* f1 = (const float*)d_in[0];
    const float* f2 = (const float*)d_in[1];
    const float* w1 = (const float*)d_in[2];
    const float* b1 = (const float*)d_in[3];
    const float* w2 = (const float*)d_in[4];
    const float* b2 = (const float*)d_in[5];
    const float* wo = (const float*)d_in[6];
    const float* bo = (const float*)d_in[7];
    float* ws  = (float*)d_ws;
    float* out = (float*)d_out;

    pack_w<<<128, 256, 0, stream>>>(w1, w2, ws);
    conv_f2<<<76, 256, 0, stream>>>(f2, b2, ws);
    mega_kernel<<<300, 256, 0, stream>>>(f1, b1, wo, bo, ws, out);
    bbx_kernel<<<NB, 256, 0, stream>>>(ws, out);
}